// Round 10
// baseline (214.408 us; speedup 1.0000x reference)
//
#include <hip/hip_runtime.h>

#define NPTS 65536
#define CCH  32
#define DDIM 64
#define GVOX (DDIM*DDIM*DDIM)   // B=1 -> 262144 voxels
#define MAXTILES 4128           // >= 65536/16 + 27 (per-class padding)
#define NSLOT (MAXTILES*16)
#define NTHREADS 1024
#define NBLOCKS  256            // 1 block/CU (55.8 KB LDS), proven co-resident (r7/r9)
#define TTOT (NTHREADS*NBLOCKS)

typedef _Float16 half8  __attribute__((ext_vector_type(8)));
typedef _Float16 half4v __attribute__((ext_vector_type(4)));
typedef float    floatx4 __attribute__((ext_vector_type(4)));

// P0 ranges: map | sorted | pcs | values->f16 | weights | zero rows | cnt+slot
#define P0N (GVOX/4 + NSLOT/4 + NSLOT/4 + (NPTS*CCH)/4 + 27*CCH*CCH + CCH + 27)

struct SharedC {
  _Float16 lw[27*CCH*CCH];   // 55296 B: all 27 taps' weights, lane-linear
  int tstart[28];
  int clsbase[27];
  int lcnt[27];
  int lbase[27];
};

// ---- monotonic spin grid-barrier (graph-capturable, bounded) ----
// bar is zeroed by hipMemsetAsync before launch; each barrier k waits for
// bar == NBLOCKS*(k+1). No reset -> no reset race. threadfence gives
// release (before arrive) / acquire (after spin) across XCDs; bounded spin
// turns a co-residency pathology into a clean FAIL instead of a hang.
__device__ __forceinline__ void gbar(int* bar, int target) {
  __syncthreads();
  if (threadIdx.x == 0) {
    __threadfence();
    atomicAdd(bar, 1);
    int guard = 1 << 24;
    while (atomicAdd(bar, 0) < target && --guard)
      __builtin_amdgcn_s_sleep(1);
    __threadfence();
  }
  __syncthreads();
}

// ---- conv phase (verified logic from mega3 / round 9) ----
// wave = 1 tile x 27 taps; batched map-gather -> srcs regs; grouped 9-wide
// A-prefetch; lane-linear LDS B-reads (conflict-free); setprio around MFMA.
template<int MODE>
__device__ void conv_phase(SharedC& sh,
    const _Float16* __restrict__ A, const int* __restrict__ map,
    const int* __restrict__ pcs, const int* __restrict__ sorted,
    const _Float16* __restrict__ WT, const float* __restrict__ bias,
    const float* __restrict__ mask, const float* __restrict__ resid,
    _Float16* __restrict__ hout, float* __restrict__ fout)
{
  for (int i = threadIdx.x; i < 3456; i += NTHREADS)
    ((half8*)sh.lw)[i] = ((const half8*)WT)[i];
  __syncthreads();

  const int wv   = threadIdx.x >> 6;       // 0..15, wave = 1 tile
  const int lane = threadIdx.x & 63;
  const int m = lane & 15, quad = lane >> 4;
  const int nt = sh.tstart[27];
  const float bi0 = bias[m], bi1 = bias[m+16];

  for (int tile = blockIdx.x*16 + wv; tile < nt; tile += NBLOCKS*16) {
    int scls = 0;
    for (int cc = 1; cc < 27; ++cc) if (tile >= sh.tstart[cc]) scls = cc;
    scls = __builtin_amdgcn_readfirstlane(scls);
    const int cz = scls/9, cy = (scls/3)%3, cx = scls%3;

    const int pc = pcs[tile*16 + m];       // slot-indexed packed coords
    const int bb = pc>>18, z = (pc>>12)&63, y = (pc>>6)&63, x = pc&63;
    const int linb = bb << 18;
    const int az[3] = { max(z-1,0)<<12, z<<12, min(z+1,DDIM-1)<<12 };
    const int ay[3] = { max(y-1,0)<<6,  y<<6,  min(y+1,DDIM-1)<<6 };
    const int ax[3] = { max(x-1,0),     x,     min(x+1,DDIM-1) };

    int srcs[27];                          // 27 independent gathers, 1 round trip
#pragma unroll
    for (int j = 0; j < 27; ++j) {
      const int jz = j/9, jy = (j/3)%3, jx = j%3;
      const int s = map[linb | az[jz] | ay[jy] | ax[jx]];
      srcs[j] = ((s < 0) ? NPTS : s) * CCH;   // empty voxel -> zero row
    }

    floatx4 acc0 = {0.f,0.f,0.f,0.f};
    floatx4 acc1 = {0.f,0.f,0.f,0.f};

#pragma unroll
    for (int g = 0; g < 3; ++g) {
      half8 av[9];
#pragma unroll
      for (int u = 0; u < 9; ++u)          // 9 independent A-gathers in flight
        av[u] = *(const half8*)(A + srcs[g*9 + u] + quad*8);
      __builtin_amdgcn_s_setprio(1);
#pragma unroll
      for (int u = 0; u < 9; ++u) {
        const int j = g*9 + u;
        const int jz = j/9, jy = (j/3)%3, jx = j%3;
        const int tz = (cz==1) ? (2-jz) : ((jz==1) ? 1 : ((cz==0) ? 0 : 2));
        const int ty = (cy==1) ? (2-jy) : ((jy==1) ? 1 : ((cy==0) ? 0 : 2));
        const int tx = (cx==1) ? (2-jx) : ((jx==1) ? 1 : ((cx==0) ? 0 : 2));
        const int t  = tz*9 + ty*3 + tx;
        const _Float16* wr = sh.lw + t*1024;  // lane l -> byte l*16, linear
        half8 b0 = *(const half8*)(wr + lane*8);
        half8 b1 = *(const half8*)(wr + 512 + lane*8);
        acc0 = __builtin_amdgcn_mfma_f32_16x16x32_f16(av[u], b0, acc0, 0, 0, 0);
        acc1 = __builtin_amdgcn_mfma_f32_16x16x32_f16(av[u], b1, acc1, 0, 0, 0);
      }
      __builtin_amdgcn_s_setprio(0);
    }

    // D layout: col(N=cout) = lane&15, row(M=point) = quad*4 + reg
#pragma unroll
    for (int reg = 0; reg < 4; ++reg) {
      const int r  = quad*4 + reg;
      const int pr = sorted[tile*16 + r];
      if (pr >= NPTS) continue;            // padded lane
      const float mk = mask[pr];
      float v0 = (acc0[reg] + mk*bi0) * mk;
      float v1 = (acc1[reg] + mk*bi1) * mk;
      if (MODE == 0) {
        v0 = fmaxf(v0, 0.f); v1 = fmaxf(v1, 0.f);
        hout[pr*CCH + m]      = (_Float16)v0;
        hout[pr*CCH + m + 16] = (_Float16)v1;
      } else {
        fout[pr*CCH + m]      = resid[pr*CCH + m]      + v0;
        fout[pr*CCH + m + 16] = resid[pr*CCH + m + 16] + v1;
      }
    }
  }
}

// ---- the fused persistent kernel (plain launch -> graph-captured & timed) ----
__global__ __launch_bounds__(1024, 4) void megak(
    const float* __restrict__ values, const int* __restrict__ idx,
    const float* __restrict__ maskv,
    const float* __restrict__ k1, const float* __restrict__ bias1,
    const float* __restrict__ k2, const float* __restrict__ bias2,
    int* __restrict__ map, int* __restrict__ sorted, int* __restrict__ pcs,
    int* __restrict__ cnt, int* __restrict__ slot,
    _Float16* __restrict__ valsh, _Float16* __restrict__ hh,
    _Float16* __restrict__ wt1, _Float16* __restrict__ wt2,
    float* __restrict__ out, int* bar)
{
  __shared__ SharedC sh;
  const int gtid = blockIdx.x*NTHREADS + threadIdx.x;

  // ---- P0: init + dtype conversion (grid-stride) ----
  for (int t0 = gtid; t0 < P0N; t0 += TTOT) {
    int tid = t0;
    if (tid < GVOX/4) { ((int4*)map)[tid] = make_int4(-1,-1,-1,-1); continue; }
    tid -= GVOX/4;
    if (tid < NSLOT/4) { ((int4*)sorted)[tid] = make_int4(NPTS,NPTS,NPTS,NPTS); continue; }
    tid -= NSLOT/4;
    if (tid < NSLOT/4) { ((int4*)pcs)[tid] = make_int4(0,0,0,0); continue; }
    tid -= NSLOT/4;
    if (tid < (NPTS*CCH)/4) {
      float4 v = ((const float4*)values)[tid];
      half4v h = { (_Float16)v.x, (_Float16)v.y, (_Float16)v.z, (_Float16)v.w };
      ((half4v*)valsh)[tid] = h; continue;
    }
    tid -= (NPTS*CCH)/4;
    if (tid < 27*CCH*CCH) {
      // (t,cin,cout) f32 -> lane-linear f16: o = t*1024 + h*512 + l*8 + i
      int t = tid/(CCH*CCH), r = tid%(CCH*CCH);
      int cin = r/CCH, cout = r%CCH;
      int h = cout >> 4, mm = cout & 15, q = cin >> 3, i = cin & 7;
      int o = t*1024 + h*512 + (q*16 + mm)*8 + i;
      wt1[o] = (_Float16)k1[tid]; wt2[o] = (_Float16)k2[tid]; continue;
    }
    tid -= 27*CCH*CCH;
    if (tid < CCH) { valsh[NPTS*CCH+tid] = (_Float16)0.f; hh[NPTS*CCH+tid] = (_Float16)0.f; continue; }
    tid -= CCH;
    if (tid < 27) { cnt[tid] = 0; slot[tid] = 0; continue; }
  }
  gbar(bar, NBLOCKS);

  // ---- P1: map + class histogram (pc/myc kept in registers) ----
  if (threadIdx.x < 27) sh.lcnt[threadIdx.x] = 0;
  __syncthreads();
  int myc = -1, mypc = 0;
  if (gtid < NPTS) {
    const int4 v = ((const int4*)idx)[gtid];
    const int b = v.x, z = v.y, y = v.z, x = v.w;
    map[((b*DDIM + z)*DDIM + y)*DDIM + x] = gtid;
    mypc = (b<<18) | (z<<12) | (y<<6) | x;
    const int cz = (z==0)?0:((z==DDIM-1)?2:1);
    const int cy = (y==0)?0:((y==DDIM-1)?2:1);
    const int cx = (x==0)?0:((x==DDIM-1)?2:1);
    myc = cz*9 + cy*3 + cx;
    atomicAdd(&sh.lcnt[myc], 1);
  }
  __syncthreads();
  if (threadIdx.x < 27 && sh.lcnt[threadIdx.x])
    atomicAdd(&cnt[threadIdx.x], sh.lcnt[threadIdx.x]);
  gbar(bar, 2*NBLOCKS);

  // ---- P2: per-block class scan (coherent atomic reads) + scatter ----
  if (threadIdx.x == 0) {
    int b = 0, tb = 0;
    for (int c = 0; c < 27; ++c) {
      const int cv = atomicAdd(&cnt[c], 0);   // device-coherent read
      sh.clsbase[c] = b; sh.tstart[c] = tb;
      const int ntc = (cv + 15) >> 4;
      b += ntc << 4; tb += ntc;
    }
    sh.tstart[27] = tb;
  }
  if (threadIdx.x < 27) sh.lcnt[threadIdx.x] = 0;
  __syncthreads();
  int lrank = 0;
  if (gtid < NPTS) lrank = atomicAdd(&sh.lcnt[myc], 1);
  __syncthreads();
  if (threadIdx.x < 27)
    sh.lbase[threadIdx.x] = sh.lcnt[threadIdx.x] ? atomicAdd(&slot[threadIdx.x], sh.lcnt[threadIdx.x]) : 0;
  __syncthreads();
  if (gtid < NPTS) {
    const int s = sh.clsbase[myc] + sh.lbase[myc] + lrank;
    sorted[s] = gtid;
    pcs[s] = mypc;
  }
  gbar(bar, 3*NBLOCKS);

  // ---- P3: conv1 (relu) ----
  conv_phase<0>(sh, valsh, map, pcs, sorted, wt1, bias1, maskv, nullptr, hh, nullptr);
  gbar(bar, 4*NBLOCKS);

  // ---- P4: conv2 (+residual) ----
  conv_phase<1>(sh, hh, map, pcs, sorted, wt2, bias2, maskv, values, nullptr, out);
}

// ---------------- launch ----------------

extern "C" void kernel_launch(void* const* d_in, const int* in_sizes, int n_in,
                              void* d_out, int out_size, void* d_ws, size_t ws_size,
                              hipStream_t stream) {
  const float* values = (const float*)d_in[0];
  const int*   indices= (const int*)  d_in[1];
  const float* maskv  = (const float*)d_in[2];
  const float* kern1  = (const float*)d_in[3];
  const float* bias1  = (const float*)d_in[4];
  const float* kern2  = (const float*)d_in[5];
  const float* bias2  = (const float*)d_in[6];
  float* out = (float*)d_out;

  char* ws = (char*)d_ws;
  size_t off = 0;
  auto alloc = [&](size_t bytes) { void* p = ws + off; off = (off + bytes + 255) & ~(size_t)255; return p; };
  int*      map     = (int*)     alloc(GVOX*4);                 // 1 MB
  int*      sorted  = (int*)     alloc(NSLOT*4);
  int*      pcs     = (int*)     alloc(NSLOT*4);
  int*      cnt     = (int*)     alloc(27*4);
  int*      slot    = (int*)     alloc(27*4);
  int*      bar     = (int*)     alloc(256);                    // spin-barrier counter
  _Float16* valsh   = (_Float16*)alloc((NPTS+1)*CCH*2);         // 4 MB
  _Float16* hh      = (_Float16*)alloc((NPTS+1)*CCH*2);         // 4 MB
  _Float16* wt1     = (_Float16*)alloc(27*CCH*CCH*2);
  _Float16* wt2     = (_Float16*)alloc(27*CCH*CCH*2);

  hipMemsetAsync(bar, 0, 4, stream);
  megak<<<NBLOCKS, NTHREADS, 0, stream>>>(
      values, indices, maskv, kern1, bias1, kern2, bias2,
      map, sorted, pcs, cnt, slot, valsh, hh, wt1, wt2, out, bar);
}